// Round 13
// baseline (89.183 us; speedup 1.0000x reference)
//
#include <hip/hip_runtime.h>
#include <hip/hip_bf16.h>
#include <stdint.h>

// Causal SDPA, B=2 H=16 S=2048 DK=64, fp32 in/out, bf16 MFMA compute.
// R13: 32x32x16 MFMA + swapped QK^T (S = mfma(K, Q) -> q is lane-local).
// P never touches LDS: exp2 in-register, packed bf16 pairs exchanged via
// shfl_xor(.,32), assembled into PV A-fragments. A/B q-tile pair fused
// INSIDE each MFMA (q-cols 0-15 = tile A, 16-31 = tile B); unified
// kv>qlim mask handles diagonal AND tile-B termination (masked cols give
// P=0 -> exact). Row-sum = in-lane adds (+1 shfl in epilogue). Grid,
// pairing (qt_a+qt_b=31, uniform 33 iters), reg-staged dbuf, prepass
// bf16 pre-swizzled ws tiles: all R5-proven, byte-identical staging.

#define SEQ   2048
#define DKK   64
#define KVB   64
#define NKT   (SEQ / KVB)    // 32
#define TILE_BYTES 16384     // 8KB K-swz + 8KB Vt-swz
#define WS_NEED ((size_t)32 * NKT * TILE_BYTES)   // 16 MB

typedef float  f32x4  __attribute__((ext_vector_type(4)));
typedef float  f32x16 __attribute__((ext_vector_type(16)));
typedef short  s16x8  __attribute__((ext_vector_type(8)));
typedef short  s16x4  __attribute__((ext_vector_type(4)));
typedef __bf16 bf16x8 __attribute__((ext_vector_type(8)));
typedef unsigned int u32x4 __attribute__((ext_vector_type(4)));

static __device__ __forceinline__ unsigned short f2b(float x) {
  union { float f; uint32_t u; } v; v.f = x;
  uint32_t r = v.u + 0x7fffu + ((v.u >> 16) & 1u);   // RNE bf16
  return (unsigned short)(r >> 16);
}
static __device__ __forceinline__ uint32_t bpack(float a, float b) {
  return ((uint32_t)f2b(b) << 16) | (uint32_t)f2b(a);
}

// Row-major [rows][64] bf16 tile, 128B rows, XOR chunk swizzle ^ (row&7).
static __device__ __forceinline__ int swzA(int row, int col) {
  return row * 128 + ((((col >> 3) ^ (row & 7)) << 4)) + ((col & 7) << 1);
}
// Vt [d][kv] bf16, swizzle ^ ((d>>1)&7).
static __device__ __forceinline__ int swzV(int d, int kv) {
  return d * 128 + ((((kv >> 3) ^ ((d >> 1) & 7)) << 4)) + ((kv & 7) << 1);
}

// ---------------- prepass: K/V fp32 -> bf16 swizzled tile images in ws ------
__global__ __launch_bounds__(256)
void prep_kv(const float* __restrict__ Kg, const float* __restrict__ Vg,
             char* __restrict__ ws) {
  const int b   = blockIdx.x;          // bh*32 + kt, 1024 blocks
  const int bh  = b >> 5, kt = b & 31;
  const int tid = threadIdx.x;
  char* tile = ws + ((size_t)b << 14);
  const size_t base = ((size_t)bh * SEQ + (size_t)kt * KVB) * DKK;
  const float* Kb = Kg + base;
  const float* Vb = Vg + base;
  {
    int col4 = tid & 15, rq = tid >> 4;
#pragma unroll
    for (int ii = 0; ii < 4; ++ii) {
      int row = ii * 16 + rq;
      f32x4 v = *(const f32x4*)(Kb + (size_t)row * DKK + col4 * 4);
      s16x4 w; w[0]=f2b(v[0]); w[1]=f2b(v[1]); w[2]=f2b(v[2]); w[3]=f2b(v[3]);
      *(s16x4*)(tile + swzA(row, col4 * 4)) = w;
    }
  }
  {
    int d0 = (tid & 15) * 4, kv0 = (tid >> 4) * 4;
    f32x4 vv[4];
#pragma unroll
    for (int r2 = 0; r2 < 4; ++r2)
      vv[r2] = *(const f32x4*)(Vb + (size_t)(kv0 + r2) * DKK + d0);
#pragma unroll
    for (int j = 0; j < 4; ++j) {
      s16x4 w; w[0]=f2b(vv[0][j]); w[1]=f2b(vv[1][j]); w[2]=f2b(vv[2][j]); w[3]=f2b(vv[3][j]);
      *(s16x4*)(tile + 8192 + swzV(d0 + j, kv0)) = w;
    }
  }
}

// ---------------- main: 32x32 MFMA, swapped QK, in-register P ---------------
__global__ __launch_bounds__(256, 2)
void attn_fwd13(const float* __restrict__ Qg, const char* __restrict__ ws,
                float* __restrict__ Og) {
  // LDS: just the 16KB KV tile (no P buffers)
  __shared__ __align__(16) char smem[TILE_BYTES];

  const int tid  = threadIdx.x;
  const int lane = tid & 63;
  const int wave = tid >> 6;
  const int h31  = lane & 31;          // q-col / kv-row / d-col within 32
  const int g2   = lane >> 5;          // k-group
  const int qmix = h31;                // mixed q index: <16 tile A, >=16 tile B

  // XCD-aware decode: 4 bh per XCD; pair p -> q-tiles (31-p, p).
  const int f     = blockIdx.x;        // 512 blocks
  const int xcd   = f & 7;
  const int inner = f >> 3;            // 0..63
  const int bh    = ((inner >> 4) << 3) | xcd;
  const int p     = inner & 15;
  const int qt_a  = 31 - p;            // 16..31
  const int qt_b  = p;                 // 0..15
  const int nkt_a = qt_a + 1;          // 17..32 (uniform 33 tile-units/block)

  const float CS = 0.18033688011f;     // (1/sqrt(64)) * log2(e)
  const size_t bhoff = (size_t)bh * SEQ * DKK;
  const float* Qb = Qg + bhoff;
  float*       Ob = Og + bhoff;
  const char*  wsb = ws + ((size_t)bh * NKT << 14);

  // this lane's q-row (B-operand col = lane&31)
  const int qglob = (qmix < 16) ? (qt_a * 64 + wave * 16 + qmix)
                                : (qt_b * 64 + wave * 16 + (qmix & 15));

  // prologue: load tile 0 into registers (256 thr x 4 x 16B)
  s16x8 st0 = *(const s16x8*)(wsb + tid * 16);
  s16x8 st1 = *(const s16x8*)(wsb + 4096 + tid * 16);
  s16x8 st2 = *(const s16x8*)(wsb + 8192 + tid * 16);
  s16x8 st3 = *(const s16x8*)(wsb + 12288 + tid * 16);

  // Q B-fragments (scale folded): qf[c4], elems d = c4*16 + g2*8 + j
  s16x8 qf[4];
#pragma unroll
  for (int c4 = 0; c4 < 4; ++c4) {
    int d0 = c4 * 16 + g2 * 8;
    f32x4 a = *(const f32x4*)(Qb + (size_t)qglob * DKK + d0);
    f32x4 b = *(const f32x4*)(Qb + (size_t)qglob * DKK + d0 + 4);
    s16x8 r;
    r[0]=f2b(a[0]*CS); r[1]=f2b(a[1]*CS); r[2]=f2b(a[2]*CS); r[3]=f2b(a[3]*CS);
    r[4]=f2b(b[0]*CS); r[5]=f2b(b[1]*CS); r[6]=f2b(b[2]*CS); r[7]=f2b(b[3]*CS);
    qf[c4] = r;
  }

  f32x16 O0 = {}, O1 = {};             // O[qreg][d: 0-31 | 32-63]
  float lacc = 0.f;                    // own-half row-sum accumulator

  char* Kl = smem;
  char* Vl = smem + 8192;

  for (int kt = 0; kt < nkt_a; ++kt) {
    __syncthreads();                   // (a) prev-iter LDS reads done
    *(s16x8*)(smem + tid * 16)         = st0;
    *(s16x8*)(smem + 4096 + tid * 16)  = st1;
    *(s16x8*)(smem + 8192 + tid * 16)  = st2;
    *(s16x8*)(smem + 12288 + tid * 16) = st3;
    if (kt + 1 < nkt_a) {              // prefetch next tile into regs
      const char* tn = wsb + ((size_t)(kt + 1) << 14);
      st0 = *(const s16x8*)(tn + tid * 16);
      st1 = *(const s16x8*)(tn + 4096 + tid * 16);
      st2 = *(const s16x8*)(tn + 8192 + tid * 16);
      st3 = *(const s16x8*)(tn + 12288 + tid * 16);
    }
    __syncthreads();                   // (b) staged tile visible

    // QK^T swapped: S[t] = K_t * Q^T -> C[kv][q], q = lane&31 (lane-local)
    f32x16 S0 = {}, S1 = {};
    __builtin_amdgcn_s_setprio(1);
#pragma unroll
    for (int c4 = 0; c4 < 4; ++c4) {
      int kcol = c4 * 16 + g2 * 8;
      s16x8 kf0 = *(const s16x8*)(Kl + swzA(h31, kcol));
      s16x8 kf1 = *(const s16x8*)(Kl + swzA(32 + h31, kcol));
      S0 = __builtin_amdgcn_mfma_f32_32x32x16_bf16(
          __builtin_bit_cast(bf16x8, kf0), __builtin_bit_cast(bf16x8, qf[c4]), S0, 0, 0, 0);
      S1 = __builtin_amdgcn_mfma_f32_32x32x16_bf16(
          __builtin_bit_cast(bf16x8, kf1), __builtin_bit_cast(bf16x8, qf[c4]), S1, 0, 0, 0);
    }
    __builtin_amdgcn_s_setprio(0);

    // P = exp2(S), unified mask (diagonal + tile-B termination):
    // S reg (t,r) holds kv_loc = t*32 + (r&3) + 8*(r>>2) + 4*g2 for q=qglob
    float Pv0[16], Pv1[16];
    if (kt >= qt_b) {
      int qr = qglob - kt * 64;        // mask iff kv_loc > qr
#pragma unroll
      for (int r = 0; r < 16; ++r) {
        int kvl = (r & 3) + 8 * (r >> 2) + 4 * g2;
        Pv0[r] = (kvl > qr) ? 0.f : exp2f(S0[r]);
        Pv1[r] = (kvl + 32 > qr) ? 0.f : exp2f(S1[r]);
      }
    } else {
#pragma unroll
      for (int r = 0; r < 16; ++r) {
        Pv0[r] = exp2f(S0[r]);
        Pv1[r] = exp2f(S1[r]);
      }
    }

    // own-half row sum (partner half added once in epilogue)
    float ls = 0.f;
#pragma unroll
    for (int r = 0; r < 16; ++r) ls += Pv0[r] + Pv1[r];
    lacc += ls;

    // pack bf16 pairs; exchange halves with partner lane (lane ^ 32)
    uint32_t pk[2][4][2], rv[2][4][2];
#pragma unroll
    for (int m = 0; m < 4; ++m) {
      pk[0][m][0] = bpack(Pv0[4 * m + 0], Pv0[4 * m + 1]);
      pk[0][m][1] = bpack(Pv0[4 * m + 2], Pv0[4 * m + 3]);
      pk[1][m][0] = bpack(Pv1[4 * m + 0], Pv1[4 * m + 1]);
      pk[1][m][1] = bpack(Pv1[4 * m + 2], Pv1[4 * m + 3]);
    }
#pragma unroll
    for (int t = 0; t < 2; ++t)
#pragma unroll
      for (int m = 0; m < 4; ++m)
#pragma unroll
        for (int i = 0; i < 2; ++i)
          rv[t][m][i] = (uint32_t)__shfl_xor((int)pk[t][m][i], 32);

    // assemble PV A-fragments: chunk c4 needs kv block B = 2*c4 + g2
    //   (t = B>>2, m = B&3); low half (kv B*8+0..3) from g2=0 side,
    //   high half (+4..7) from g2=1 side.
    s16x8 pf[4];
#pragma unroll
    for (int c4 = 0; c4 < 4; ++c4) {
      int t = c4 >> 1, mb = (c4 & 1) * 2;
      u32x4 u;
      u[0] = g2 ? rv[t][mb + 1][0] : pk[t][mb][0];
      u[1] = g2 ? rv[t][mb + 1][1] : pk[t][mb][1];
      u[2] = g2 ? pk[t][mb + 1][0] : rv[t][mb][0];
      u[3] = g2 ? pk[t][mb + 1][1] : rv[t][mb][1];
      pf[c4] = __builtin_bit_cast(s16x8, u);
    }

    // PV: O[q][d] += P * V  (A = P in-reg, B = Vt from LDS)
    __builtin_amdgcn_s_setprio(1);
#pragma unroll
    for (int c4 = 0; c4 < 4; ++c4) {
      int kcol = c4 * 16 + g2 * 8;
      s16x8 vf0 = *(const s16x8*)(Vl + swzV(h31, kcol));
      s16x8 vf1 = *(const s16x8*)(Vl + swzV(32 + h31, kcol));
      O0 = __builtin_amdgcn_mfma_f32_32x32x16_bf16(
          __builtin_bit_cast(bf16x8, pf[c4]), __builtin_bit_cast(bf16x8, vf0), O0, 0, 0, 0);
      O1 = __builtin_amdgcn_mfma_f32_32x32x16_bf16(
          __builtin_bit_cast(bf16x8, pf[c4]), __builtin_bit_cast(bf16x8, vf1), O1, 0, 0, 0);
    }
    __builtin_amdgcn_s_setprio(0);
  }

  // epilogue: full row-sum, normalize, store
  float lt = lacc + __shfl_xor(lacc, 32);   // lanes qm and qm+32 hold l[qm]
#pragma unroll
  for (int r = 0; r < 16; ++r) {
    int qm = (r & 3) + 8 * (r >> 2) + 4 * g2;   // O-row mixed-q index
    float linv = 1.f / __shfl(lt, qm);
    int row = (qm < 16) ? (qt_a * 64 + wave * 16 + qm)
                        : (qt_b * 64 + wave * 16 + (qm & 15));
    Ob[(size_t)row * DKK + h31]      = O0[r] * linv;
    Ob[(size_t)row * DKK + 32 + h31] = O1[r] * linv;
  }
}

// ---------------- fallback: self-staging (only if ws too small) -------------
__global__ __launch_bounds__(256, 2)
void attn_fwd_fb(const float* __restrict__ Qg, const float* __restrict__ Kg,
                 const float* __restrict__ Vg, float* __restrict__ Og) {
  __shared__ __align__(16) char smem[8192 + 8192 + 8 * 2048];
  char* Kl = smem;
  char* Vl = smem + 8192;
  const int tid  = threadIdx.x;
  const int lane = tid & 63;
  const int wave = tid >> 6;
  const int c    = lane & 15;
  const int g    = lane >> 4;
  const int f    = blockIdx.x;
  const int xcd  = f & 7;
  const int inner= f >> 3;
  const int bh   = ((inner >> 4) << 3) | xcd;
  const int qt   = 15 - (inner & 15);
  const float CS = 0.18033688011f;
  const size_t bhoff = (size_t)bh * SEQ * DKK;
  const float* Qb = Qg + bhoff;
  const float* Kb = Kg + bhoff;
  const float* Vb = Vg + bhoff;
  float*       Ob = Og + bhoff;
  s16x8 qf[2][2];
#pragma unroll
  for (int u = 0; u < 2; ++u) {
    int qrow = qt * 128 + wave * 32 + u * 16 + c;
#pragma unroll
    for (int h = 0; h < 2; ++h) {
      int d0 = h * 32 + g * 8;
      const f32x4* pq = (const f32x4*)(Qb + (size_t)qrow * DKK + d0);
      f32x4 a = pq[0], b = pq[1];
      s16x8 r;
      r[0]=f2b(a[0]*CS); r[1]=f2b(a[1]*CS); r[2]=f2b(a[2]*CS); r[3]=f2b(a[3]*CS);
      r[4]=f2b(b[0]*CS); r[5]=f2b(b[1]*CS); r[6]=f2b(b[2]*CS); r[7]=f2b(b[3]*CS);
      qf[u][h] = r;
    }
  }
  f32x4 O[2][4] = {};
  float m[2][4], l[2][4];
#pragma unroll
  for (int u = 0; u < 2; ++u)
#pragma unroll
    for (int r = 0; r < 4; ++r) { m[u][r] = -1e30f; l[u][r] = 0.f; }
  const int nkt = 2 * qt + 2;
  for (int kt = 0; kt < nkt; ++kt) {
    __syncthreads();
    {
      int col4 = tid & 15, rq = tid >> 4;
#pragma unroll
      for (int ii = 0; ii < 4; ++ii) {
        int row = ii * 16 + rq;
        f32x4 v = *(const f32x4*)(Kb + (size_t)(kt * KVB + row) * DKK + col4 * 4);
        s16x4 w; w[0]=f2b(v[0]); w[1]=f2b(v[1]); w[2]=f2b(v[2]); w[3]=f2b(v[3]);
        *(s16x4*)(Kl + swzA(row, col4 * 4)) = w;
      }
      int d0 = (tid & 15) * 4, kv0 = (tid >> 4) * 4;
      f32x4 vv[4];
#pragma unroll
      for (int r2 = 0; r2 < 4; ++r2)
        vv[r2] = *(const f32x4*)(Vb + (size_t)(kt * KVB + kv0 + r2) * DKK + d0);
#pragma unroll
      for (int j = 0; j < 4; ++j) {
        s16x4 w; w[0]=f2b(vv[0][j]); w[1]=f2b(vv[1][j]); w[2]=f2b(vv[2][j]); w[3]=f2b(vv[3][j]);
        *(s16x4*)(Vl + swzV(d0 + j, kv0)) = w;
      }
    }
    __syncthreads();
    f32x4 S[2][4] = {};
#pragma unroll
    for (int s = 0; s < 4; ++s)
#pragma unroll
      for (int h = 0; h < 2; ++h) {
        s16x8 kf = *(const s16x8*)(Kl + swzA(s * 16 + c, h * 32 + g * 8));
#pragma unroll
        for (int u = 0; u < 2; ++u)
          S[u][s] = __builtin_amdgcn_mfma_f32_16x16x32_bf16(
              __builtin_bit_cast(bf16x8, qf[u][h]),
              __builtin_bit_cast(bf16x8, kf), S[u][s], 0, 0, 0);
      }
    if (kt >= nkt - 2) {
#pragma unroll
      for (int u = 0; u < 2; ++u) {
        int qrb = qt * 128 + wave * 32 + u * 16 + g * 4;
#pragma unroll
        for (int s = 0; s < 4; ++s) {
          int kv = kt * KVB + s * 16 + c;
#pragma unroll
          for (int r = 0; r < 4; ++r)
            if (kv > qrb + r) S[u][s][r] = -1e30f;
        }
      }
    }
#pragma unroll
    for (int u = 0; u < 2; ++u) {
      char* Pl = smem + 16384 + (wave * 2 + u) * 2048;
#pragma unroll
      for (int r = 0; r < 4; ++r) {
        float t0 = fmaxf(fmaxf(S[u][0][r], S[u][1][r]),
                         fmaxf(S[u][2][r], S[u][3][r]));
#pragma unroll
        for (int off = 1; off <= 8; off <<= 1)
          t0 = fmaxf(t0, __shfl_xor(t0, off));
        float mn   = fmaxf(m[u][r], t0);
        float corr = exp2f(m[u][r] - mn);
        float ps = 0.f;
#pragma unroll
        for (int s = 0; s < 4; ++s) {
          float pv = exp2f(S[u][s][r] - mn);
          ps += pv;
          *(unsigned short*)(Pl + swzA(g * 4 + r, s * 16 + c)) = f2b(pv);
        }
#pragma unroll
        for (int off = 1; off <= 8; off <<= 1)
          ps += __shfl_xor(ps, off);
        l[u][r] = l[u][r] * corr + ps;
        m[u][r] = mn;
#pragma unroll
        for (int t = 0; t < 4; ++t) O[u][t][r] *= corr;
      }
    }
#pragma unroll
    for (int ch = 0; ch < 2; ++ch) {
      s16x8 pa[2];
#pragma unroll
      for (int u = 0; u < 2; ++u)
        pa[u] = *(const s16x8*)(smem + 16384 + (wave * 2 + u) * 2048
                                + swzA(c, ch * 32 + g * 8));
#pragma unroll
      for (int t = 0; t < 4; ++t) {
        s16x8 vb = *(const s16x8*)(Vl + swzV(t * 16 + c, ch * 32 + g * 8));
#pragma unroll
        for (int u = 0; u < 2; ++u)
          O[u][t] = __builtin_amdgcn_mfma_f32_16x16x32_bf16(
              __builtin_bit_cast(bf16x8, pa[u]),
              __builtin_bit_cast(bf16x8, vb), O[u][t], 0, 0, 0);
      }
    }
  }
#pragma unroll
  for (int u = 0; u < 2; ++u)
#pragma unroll
    for (int r = 0; r < 4; ++r) {
      int qrow = qt * 128 + wave * 32 + u * 16 + g * 4 + r;
      float inv = 1.f / l[u][r];
#pragma unroll
      for (int t = 0; t < 4; ++t)
        Ob[(size_t)qrow * DKK + t * 16 + c] = O[u][t][r] * inv;
    }
}

extern "C" void kernel_launch(void* const* d_in, const int* in_sizes, int n_in,
                              void* d_out, int out_size, void* d_ws, size_t ws_size,
                              hipStream_t stream) {
  const float* Q = (const float*)d_in[0];
  const float* K = (const float*)d_in[1];
  const float* V = (const float*)d_in[2];
  float* O = (float*)d_out;
  (void)in_sizes; (void)n_in; (void)out_size;
  if (ws_size >= WS_NEED) {
    char* ws = (char*)d_ws;
    prep_kv<<<dim3(32 * NKT), dim3(256), 0, stream>>>(K, V, ws);
    attn_fwd13<<<dim3(512), dim3(256), 0, stream>>>(Q, ws, O);
  } else {
    attn_fwd_fb<<<dim3(512), dim3(256), 0, stream>>>(Q, K, V, O);
  }
}